// Round 1
// baseline (68.407 us; speedup 1.0000x reference)
//
#include <hip/hip_runtime.h>
#include <stdint.h>

#define S_TOK 8192
#define D_DIM 768
#define B_SZ  4
#define K_TOP 512

// ---------------- Kernel 1: importance[s] = 0.25 * sum_b ||h[b,s,:]|| ----------------
// One wave (64 lanes) per token. Per batch row: 768 floats = 192 float4, 3 per lane.
__global__ __launch_bounds__(256) void importance_kernel(const float4* __restrict__ h4,
                                                         float* __restrict__ imp) {
    const int D4 = D_DIM / 4; // 192
    int wave = (blockIdx.x * blockDim.x + threadIdx.x) >> 6;
    int lane = threadIdx.x & 63;
    if (wave >= S_TOK) return;
    float acc = 0.f;
#pragma unroll
    for (int b = 0; b < B_SZ; ++b) {
        const float4* row = h4 + ((size_t)b * S_TOK + (size_t)wave) * D4;
        float ss = 0.f;
#pragma unroll
        for (int j = 0; j < 3; ++j) {
            float4 v = row[lane + 64 * j];
            ss += v.x * v.x + v.y * v.y + v.z * v.z + v.w * v.w;
        }
#pragma unroll
        for (int off = 32; off >= 1; off >>= 1) ss += __shfl_xor(ss, off);
        acc += sqrtf(ss);
    }
    if (lane == 0) imp[wave] = acc * 0.25f;
}

// ---------------- Kernel 2: exact top-512 (value desc, index asc on ties) ----------------
// Single block, 1024 threads. Radix-select the 512th-largest key (values >= 0 so
// float bits compare as uint32), collect >T via atomic, pick tied==T elements by
// ascending index via block scan, then bitonic-sort 512 composite keys.
__global__ __launch_bounds__(1024) void topk_kernel(const float* __restrict__ imp,
                                                    int* __restrict__ topk) {
    const int NT = 1024;
    const int tid = threadIdx.x;
    __shared__ uint32_t s_keys[S_TOK];           // 32 KB
    __shared__ uint32_t s_hist[256];
    __shared__ uint32_t s_scan[1024];            // 4 KB
    __shared__ unsigned long long s_sel[K_TOP];  // 4 KB
    __shared__ uint32_t s_prefix, s_want, s_cntgt;

    for (int i = tid; i < S_TOK; i += NT) s_keys[i] = __float_as_uint(imp[i]);
    if (tid == 0) { s_prefix = 0u; s_want = K_TOP; s_cntgt = 0u; }
    __syncthreads();

    // --- radix select: find T = 512th largest key ---
    uint32_t dmask = 0u;
    for (int shift = 24; shift >= 0; shift -= 8) {
        for (int b = tid; b < 256; b += NT) s_hist[b] = 0u;
        __syncthreads();
        uint32_t pfx = s_prefix;
        for (int i = tid; i < S_TOK; i += NT) {
            uint32_t k = s_keys[i];
            if ((k & dmask) == pfx) atomicAdd(&s_hist[(k >> shift) & 0xFFu], 1u);
        }
        __syncthreads();
        if (tid == 0) {
            uint32_t want = s_want;
            int b = 255;
            for (; b > 0; --b) {
                uint32_t c = s_hist[b];
                if (want <= c) break;
                want -= c;
            }
            s_want = want;
            s_prefix = pfx | ((uint32_t)b << shift);
        }
        dmask |= (0xFFu << shift);
        __syncthreads();
    }
    const uint32_t T = s_prefix;
    const uint32_t need_eq = s_want;  // how many ==T elements to take (lowest indices)

    // --- collect strictly-greater elements (order fixed later by sort) ---
    for (int i = tid; i < S_TOK; i += NT) {
        uint32_t k = s_keys[i];
        if (k > T) {
            uint32_t p = atomicAdd(&s_cntgt, 1u);
            s_sel[p] = ((unsigned long long)k << 32) | (uint32_t)(~(uint32_t)i);
        }
    }
    __syncthreads();
    const uint32_t cntgt = s_cntgt;  // == K_TOP - need_eq

    // --- pick need_eq smallest-index elements with key == T via block scan ---
    const int PER = S_TOK / NT;  // 8 contiguous elements per thread
    int my0 = tid * PER;
    uint32_t loc = 0;
#pragma unroll
    for (int j = 0; j < PER; ++j) loc += (s_keys[my0 + j] == T) ? 1u : 0u;
    s_scan[tid] = loc;
    __syncthreads();
    for (int off = 1; off < NT; off <<= 1) {  // Hillis-Steele inclusive scan
        uint32_t v = (tid >= off) ? s_scan[tid - off] : 0u;
        __syncthreads();
        s_scan[tid] += v;
        __syncthreads();
    }
    uint32_t rank = s_scan[tid] - loc;  // exclusive prefix among ==T elements
#pragma unroll
    for (int j = 0; j < PER; ++j) {
        if (s_keys[my0 + j] == T) {
            if (rank < need_eq)
                s_sel[cntgt + rank] =
                    ((unsigned long long)T << 32) | (uint32_t)(~(uint32_t)(my0 + j));
            ++rank;
        }
    }
    __syncthreads();

    // --- bitonic sort 512 composite keys, descending ---
    for (int k2 = 2; k2 <= K_TOP; k2 <<= 1) {
        for (int j = k2 >> 1; j > 0; j >>= 1) {
            for (int i = tid; i < K_TOP; i += NT) {
                int ixj = i ^ j;
                if (ixj > i) {
                    unsigned long long a = s_sel[i], b = s_sel[ixj];
                    bool desc = ((i & k2) == 0);
                    if (desc ? (a < b) : (a > b)) { s_sel[i] = b; s_sel[ixj] = a; }
                }
            }
            __syncthreads();
        }
    }
    for (int i = tid; i < K_TOP; i += NT)
        topk[i] = (int)(~(uint32_t)(s_sel[i] & 0xFFFFFFFFull));
}

// ---------------- Kernel 3: out[i,:] = 0.25 * sum_b h[b, topk[i], :] ----------------
// One block per output row; 192 threads x float4 = 768 floats, coalesced.
__global__ __launch_bounds__(192) void gather_kernel(const float4* __restrict__ h4,
                                                     const int* __restrict__ topk,
                                                     float4* __restrict__ out4) {
    const int D4 = D_DIM / 4;  // 192
    const size_t SD4 = (size_t)S_TOK * D4;
    int row = blockIdx.x;
    int idx = topk[row];
    const float4* base = h4 + (size_t)idx * D4;
    int d = threadIdx.x;
    float4 a = base[d];
    float4 b = base[d + SD4];
    float4 c = base[d + 2 * SD4];
    float4 e = base[d + 3 * SD4];
    float4 r;
    r.x = 0.25f * (a.x + b.x + c.x + e.x);
    r.y = 0.25f * (a.y + b.y + c.y + e.y);
    r.z = 0.25f * (a.z + b.z + c.z + e.z);
    r.w = 0.25f * (a.w + b.w + c.w + e.w);
    out4[(size_t)row * D4 + d] = r;
}

extern "C" void kernel_launch(void* const* d_in, const int* in_sizes, int n_in,
                              void* d_out, int out_size, void* d_ws, size_t ws_size,
                              hipStream_t stream) {
    const float* h = (const float*)d_in[0];
    // d_in[1] (memory) is dead: k == MEMORY_SIZE, every row is overwritten.
    float* out = (float*)d_out;
    float* imp = (float*)d_ws;
    int* topk = (int*)((char*)d_ws + S_TOK * sizeof(float));

    importance_kernel<<<S_TOK / 4, 256, 0, stream>>>((const float4*)h, imp);
    topk_kernel<<<1, 1024, 0, stream>>>(imp, topk);
    gather_kernel<<<K_TOP, 192, 0, stream>>>((const float4*)h, topk, (float4*)out);
}

// Round 2
// 46.089 us; speedup vs baseline: 1.4842x; 1.4842x over previous
//
#include <hip/hip_runtime.h>
#include <stdint.h>

#define S_TOK 8192
#define D_DIM 768
#define B_SZ  4
#define K_TOP 512

// ---------------- Kernel 1: importance[s] = 0.25 * sum_b ||h[b,s,:]|| ----------------
// One wave (64 lanes) per token. Per batch row: 768 floats = 192 float4, 3 per lane.
__global__ __launch_bounds__(256) void importance_kernel(const float4* __restrict__ h4,
                                                         float* __restrict__ imp) {
    const int D4 = D_DIM / 4; // 192
    int wave = (blockIdx.x * blockDim.x + threadIdx.x) >> 6;
    int lane = threadIdx.x & 63;
    if (wave >= S_TOK) return;
    float acc = 0.f;
#pragma unroll
    for (int b = 0; b < B_SZ; ++b) {
        const float4* row = h4 + ((size_t)b * S_TOK + (size_t)wave) * D4;
        float ss = 0.f;
#pragma unroll
        for (int j = 0; j < 3; ++j) {
            float4 v = row[lane + 64 * j];
            ss += v.x * v.x + v.y * v.y + v.z * v.z + v.w * v.w;
        }
#pragma unroll
        for (int off = 32; off >= 1; off >>= 1) ss += __shfl_xor(ss, off);
        acc += sqrtf(ss);
    }
    if (lane == 0) imp[wave] = acc * 0.25f;
}

// ---------------- Kernel 2: exact top-512 (value desc, index asc on ties) ----------------
// Single block, 1024 threads. Radix-select the 512th-largest key (values >= 0 so
// float bits compare as uint32). All phases parallel: wave-shuffle suffix scan for
// bin select, wave-level scans for the ==T pick, brute-force rank instead of sort.
__global__ __launch_bounds__(1024) void topk_kernel(const float* __restrict__ imp,
                                                    int* __restrict__ topk) {
    const int NT = 1024;
    const int tid = threadIdx.x;
    const int lane = tid & 63;
    const int wid = tid >> 6;  // 16 waves
    __shared__ uint32_t s_keys[S_TOK];           // 32 KB
    __shared__ uint32_t s_hist[256];
    __shared__ uint32_t s_wsum[16];
    __shared__ unsigned long long s_sel[K_TOP];  // 4 KB
    __shared__ uint32_t s_prefix, s_want, s_cntgt;

    for (int i = tid; i < S_TOK; i += NT) s_keys[i] = __float_as_uint(imp[i]);
    if (tid == 0) { s_prefix = 0u; s_want = K_TOP; s_cntgt = 0u; }
    __syncthreads();

    // --- radix select: find T = 512th largest key ---
    uint32_t dmask = 0u;
    for (int shift = 24; shift >= 0; shift -= 8) {
        if (tid < 256) s_hist[tid] = 0u;
        __syncthreads();
        const uint32_t pfx = s_prefix;
        const uint32_t want_in = s_want;
        for (int i = tid; i < S_TOK; i += NT) {
            uint32_t k = s_keys[i];
            if ((k & dmask) == pfx) atomicAdd(&s_hist[(k >> shift) & 0xFFu], 1u);
        }
        __syncthreads();
        if (wid == 0) {  // wave 0: parallel suffix scan over 256 bins, 4 bins/lane
            uint32_t c0 = s_hist[4 * lane + 0];
            uint32_t c1 = s_hist[4 * lane + 1];
            uint32_t c2 = s_hist[4 * lane + 2];
            uint32_t c3 = s_hist[4 * lane + 3];
            uint32_t ls = c0 + c1 + c2 + c3;
            uint32_t s = ls;  // inclusive suffix sum across lanes
            for (int off = 1; off < 64; off <<= 1) {
                uint32_t v = __shfl_down(s, off);
                if (lane + off < 64) s += v;
            }
            uint32_t above = s - ls;          // strict suffix (lanes > lane)
            uint32_t sstr3 = above;           // strict-suffix per bin, from top
            uint32_t sstr2 = sstr3 + c3;
            uint32_t sstr1 = sstr2 + c2;
            uint32_t sstr0 = sstr1 + c1;
            const uint32_t w = want_in;
            int b = -1; uint32_t nw = 0;
            if      (sstr3 < w && w <= sstr3 + c3) { b = 4 * lane + 3; nw = w - sstr3; }
            else if (sstr2 < w && w <= sstr2 + c2) { b = 4 * lane + 2; nw = w - sstr2; }
            else if (sstr1 < w && w <= sstr1 + c1) { b = 4 * lane + 1; nw = w - sstr1; }
            else if (sstr0 < w && w <= sstr0 + c0) { b = 4 * lane + 0; nw = w - sstr0; }
            if (b >= 0) {  // exactly one lane hits
                s_prefix = pfx | ((uint32_t)b << shift);
                s_want = nw;
            }
        }
        dmask |= (0xFFu << shift);
        __syncthreads();
    }
    const uint32_t T = s_prefix;
    const uint32_t need_eq = s_want;  // # of ==T elements to take (lowest indices)

    // --- collect strictly-greater elements (order fixed later by rank) ---
    for (int i = tid; i < S_TOK; i += NT) {
        uint32_t k = s_keys[i];
        if (k > T) {
            uint32_t p = atomicAdd(&s_cntgt, 1u);
            s_sel[p] = ((unsigned long long)k << 32) | (uint32_t)(~(uint32_t)i);
        }
    }
    __syncthreads();
    const uint32_t cntgt = s_cntgt;  // == K_TOP - need_eq

    // --- pick need_eq smallest-index ==T elements via wave-level scans ---
    const int PER = S_TOK / NT;  // 8 contiguous elements per thread
    const int my0 = tid * PER;
    uint32_t loc = 0;
#pragma unroll
    for (int j = 0; j < PER; ++j) loc += (s_keys[my0 + j] == T) ? 1u : 0u;
    uint32_t incl = loc;  // wave inclusive scan
    for (int off = 1; off < 64; off <<= 1) {
        uint32_t v = __shfl_up(incl, off);
        if (lane >= off) incl += v;
    }
    if (lane == 63) s_wsum[wid] = incl;
    __syncthreads();
    uint32_t wbase = 0;
    for (int wj = 0; wj < wid; ++wj) wbase += s_wsum[wj];  // 16 broadcast reads
    uint32_t rank = wbase + incl - loc;  // exclusive prefix among ==T elements
#pragma unroll
    for (int j = 0; j < PER; ++j) {
        if (s_keys[my0 + j] == T) {
            if (rank < need_eq)
                s_sel[cntgt + rank] =
                    ((unsigned long long)T << 32) | (uint32_t)(~(uint32_t)(my0 + j));
            ++rank;
        }
    }
    __syncthreads();

    // --- brute-force rank (replaces bitonic sort): keys are unique (index embedded)
    if (tid < K_TOP) {
        const unsigned long long a = s_sel[tid];
        uint32_t r = 0;
        for (int j = 0; j < K_TOP; ++j) r += (s_sel[j] > a) ? 1u : 0u;  // broadcast reads
        topk[r] = (int)(~(uint32_t)(a & 0xFFFFFFFFull));
    }
}

// ---------------- Kernel 3: out[i,:] = 0.25 * sum_b h[b, topk[i], :] ----------------
// One block per output row; 192 threads x float4 = 768 floats, coalesced.
__global__ __launch_bounds__(192) void gather_kernel(const float4* __restrict__ h4,
                                                     const int* __restrict__ topk,
                                                     float4* __restrict__ out4) {
    const int D4 = D_DIM / 4;  // 192
    const size_t SD4 = (size_t)S_TOK * D4;
    int row = blockIdx.x;
    int idx = topk[row];
    const float4* base = h4 + (size_t)idx * D4;
    int d = threadIdx.x;
    float4 a = base[d];
    float4 b = base[d + SD4];
    float4 c = base[d + 2 * SD4];
    float4 e = base[d + 3 * SD4];
    float4 r;
    r.x = 0.25f * (a.x + b.x + c.x + e.x);
    r.y = 0.25f * (a.y + b.y + c.y + e.y);
    r.z = 0.25f * (a.z + b.z + c.z + e.z);
    r.w = 0.25f * (a.w + b.w + c.w + e.w);
    out4[(size_t)row * D4 + d] = r;
}

extern "C" void kernel_launch(void* const* d_in, const int* in_sizes, int n_in,
                              void* d_out, int out_size, void* d_ws, size_t ws_size,
                              hipStream_t stream) {
    const float* h = (const float*)d_in[0];
    // d_in[1] (memory) is dead: k == MEMORY_SIZE, every row is overwritten.
    float* out = (float*)d_out;
    float* imp = (float*)d_ws;
    int* topk = (int*)((char*)d_ws + S_TOK * sizeof(float));

    importance_kernel<<<S_TOK / 4, 256, 0, stream>>>((const float4*)h, imp);
    topk_kernel<<<1, 1024, 0, stream>>>(imp, topk);
    gather_kernel<<<K_TOP, 192, 0, stream>>>((const float4*)h, topk, (float4*)out);
}

// Round 3
// 39.551 us; speedup vs baseline: 1.7296x; 1.1653x over previous
//
#include <hip/hip_runtime.h>
#include <stdint.h>

#define S_TOK 8192
#define D_DIM 768
#define B_SZ  4
#define K_TOP 512

// ---------------- Kernel 1: importance[s] = 0.25 * sum_b ||h[b,s,:]|| ----------------
// One wave (64 lanes) per token. Per batch row: 768 floats = 192 float4, 3 per lane.
__global__ __launch_bounds__(256) void importance_kernel(const float4* __restrict__ h4,
                                                         float* __restrict__ imp) {
    const int D4 = D_DIM / 4; // 192
    int wave = (blockIdx.x * blockDim.x + threadIdx.x) >> 6;
    int lane = threadIdx.x & 63;
    if (wave >= S_TOK) return;
    float acc = 0.f;
#pragma unroll
    for (int b = 0; b < B_SZ; ++b) {
        const float4* row = h4 + ((size_t)b * S_TOK + (size_t)wave) * D4;
        float ss = 0.f;
#pragma unroll
        for (int j = 0; j < 3; ++j) {
            float4 v = row[lane + 64 * j];
            ss += v.x * v.x + v.y * v.y + v.z * v.z + v.w * v.w;
        }
#pragma unroll
        for (int off = 32; off >= 1; off >>= 1) ss += __shfl_xor(ss, off);
        acc += sqrtf(ss);
    }
    if (lane == 0) imp[wave] = acc * 0.25f;
}

// ---------------- Kernel 2 (fused): block r selects rank-r element, gathers row r ----
// 512 blocks x 512 threads. Radix-select rank r+1 (values >= 0 so float bits compare
// as uint32) with per-wave replicated histograms + ballot-uniform fast path, then
// pick the need-th smallest-index ==T element via wave scans, then gather+mean.
__global__ __launch_bounds__(512) void select_gather_kernel(const float* __restrict__ imp,
                                                            const float4* __restrict__ h4,
                                                            float4* __restrict__ out4) {
    const int NT = 512;
    const int tid = threadIdx.x;
    const int lane = tid & 63;
    const int wid = tid >> 6;  // 8 waves
    __shared__ uint32_t s_keys[S_TOK];      // 32 KB
    __shared__ uint32_t s_hist[8][256];     // 8 KB, one copy per wave
    __shared__ uint32_t s_red[8];
    __shared__ uint32_t s_prefix, s_want;
    __shared__ int s_idx;

    // --- load imp bits into LDS (coalesced float4 -> uint4 writes) ---
    const uint4* imp4 = (const uint4*)imp;  // bit pattern only
#pragma unroll
    for (int k = 0; k < 4; ++k) {
        uint4 v = imp4[tid + k * NT];
        ((uint4*)s_keys)[tid + k * NT] = v;
    }
    if (tid == 0) { s_prefix = 0u; s_want = (uint32_t)blockIdx.x + 1u; s_idx = 0; }
    __syncthreads();

    // --- radix select: find T = (blockIdx.x+1)-th largest key ---
    uint32_t dmask = 0u;
    for (int shift = 24; shift >= 0; shift -= 8) {
        ((uint4*)s_hist)[tid] = make_uint4(0u, 0u, 0u, 0u);  // 2048 words / 512 thr
        __syncthreads();
        const uint32_t pfx = s_prefix;
        const uint32_t want_in = s_want;
        uint32_t* mh = s_hist[wid];
#pragma unroll
        for (int k = 0; k < 4; ++k) {
            uint4 kv = ((const uint4*)s_keys)[tid + k * NT];
            uint32_t ks[4] = {kv.x, kv.y, kv.z, kv.w};
#pragma unroll
            for (int j = 0; j < 4; ++j) {
                uint32_t key = ks[j];
                bool active = ((key & dmask) == pfx);
                uint32_t bin = (key >> shift) & 0xFFu;
                unsigned long long act = __ballot(active);
                if (act) {
                    int fl = __ffsll(act) - 1;
                    uint32_t b0 = __shfl(bin, fl);
                    unsigned long long same = __ballot(active && (bin == b0));
                    if (same == act) {  // wave-uniform digit: single plain add
                        if (lane == fl) mh[b0] += (uint32_t)__popcll(act);
                    } else if (active) {
                        atomicAdd(&mh[bin], 1u);
                    }
                }
            }
        }
        __syncthreads();
        if (wid == 0) {  // wave 0: sum 8 copies, parallel suffix scan, pick bin
            uint4 a = make_uint4(0u, 0u, 0u, 0u);
#pragma unroll
            for (int w = 0; w < 8; ++w) {
                uint4 v = ((const uint4*)(s_hist[w]))[lane];
                a.x += v.x; a.y += v.y; a.z += v.z; a.w += v.w;
            }
            uint32_t c0 = a.x, c1 = a.y, c2 = a.z, c3 = a.w;
            uint32_t ls = c0 + c1 + c2 + c3;
            uint32_t s = ls;  // inclusive suffix sum across lanes
            for (int off = 1; off < 64; off <<= 1) {
                uint32_t v = __shfl_down(s, off);
                if (lane + off < 64) s += v;
            }
            uint32_t above = s - ls;   // strict suffix (lanes > lane)
            uint32_t sstr3 = above;
            uint32_t sstr2 = sstr3 + c3;
            uint32_t sstr1 = sstr2 + c2;
            uint32_t sstr0 = sstr1 + c1;
            const uint32_t w = want_in;
            int b = -1; uint32_t nw = 0;
            if      (sstr3 < w && w <= sstr3 + c3) { b = 4 * lane + 3; nw = w - sstr3; }
            else if (sstr2 < w && w <= sstr2 + c2) { b = 4 * lane + 2; nw = w - sstr2; }
            else if (sstr1 < w && w <= sstr1 + c1) { b = 4 * lane + 1; nw = w - sstr1; }
            else if (sstr0 < w && w <= sstr0 + c0) { b = 4 * lane + 0; nw = w - sstr0; }
            if (b >= 0) {  // exactly one lane hits
                s_prefix = pfx | ((uint32_t)b << shift);
                s_want = nw;
            }
        }
        dmask |= (0xFFu << shift);
        __syncthreads();
    }
    const uint32_t T = s_prefix;
    const uint32_t need = s_want;  // pick the need-th smallest-index ==T element

    // --- find that element: per-thread contiguous chunk of 16, wave scans ---
    const int my0 = tid * 16;
    uint32_t kk[16];
#pragma unroll
    for (int jj = 0; jj < 4; ++jj) {
        int j = (jj + (lane >> 1)) & 3;  // rotate to spread LDS banks
        uint4 v = ((const uint4*)s_keys)[tid * 4 + j];
        kk[4 * j + 0] = v.x; kk[4 * j + 1] = v.y;
        kk[4 * j + 2] = v.z; kk[4 * j + 3] = v.w;
    }
    uint32_t cnt = 0;
#pragma unroll
    for (int j = 0; j < 16; ++j) cnt += (kk[j] == T) ? 1u : 0u;
    uint32_t incl = cnt;  // wave inclusive scan
    for (int off = 1; off < 64; off <<= 1) {
        uint32_t v = __shfl_up(incl, off);
        if (lane >= off) incl += v;
    }
    if (lane == 63) s_red[wid] = incl;
    __syncthreads();
    uint32_t wbase = 0;
    for (int wj = 0; wj < wid; ++wj) wbase += s_red[wj];
    uint32_t p = wbase + incl - cnt;  // exclusive prefix among ==T elements
#pragma unroll
    for (int j = 0; j < 16; ++j) {
        if (kk[j] == T) {
            ++p;
            if (p == need) s_idx = my0 + j;
        }
    }
    __syncthreads();

    // --- gather: out[r,:] = 0.25 * sum_b h[b, idx, :] ---
    const int idx = s_idx;
    if (tid < D_DIM / 4) {  // 192 threads, one float4 each
        const int D4 = D_DIM / 4;
        const size_t SD4 = (size_t)S_TOK * D4;
        const float4* base = h4 + (size_t)idx * D4;
        float4 a = base[tid];
        float4 b = base[tid + SD4];
        float4 c = base[tid + 2 * SD4];
        float4 e = base[tid + 3 * SD4];
        float4 r;
        r.x = 0.25f * (a.x + b.x + c.x + e.x);
        r.y = 0.25f * (a.y + b.y + c.y + e.y);
        r.z = 0.25f * (a.z + b.z + c.z + e.z);
        r.w = 0.25f * (a.w + b.w + c.w + e.w);
        out4[(size_t)blockIdx.x * D4 + tid] = r;
    }
}

extern "C" void kernel_launch(void* const* d_in, const int* in_sizes, int n_in,
                              void* d_out, int out_size, void* d_ws, size_t ws_size,
                              hipStream_t stream) {
    const float* h = (const float*)d_in[0];
    // d_in[1] (memory) is dead: k == MEMORY_SIZE, every row is overwritten.
    float* out = (float*)d_out;
    float* imp = (float*)d_ws;

    importance_kernel<<<S_TOK / 4, 256, 0, stream>>>((const float4*)h, imp);
    select_gather_kernel<<<K_TOP, 512, 0, stream>>>(imp, (const float4*)h, (float4*)out);
}

// Round 4
// 39.437 us; speedup vs baseline: 1.7346x; 1.0029x over previous
//
#include <hip/hip_runtime.h>
#include <stdint.h>

#define S_TOK 8192
#define D_DIM 768
#define B_SZ  4
#define K_TOP 512
#define NSLICE 32
#define SLICE (S_TOK / NSLICE)  // 256

// ---------------- Kernel 1: importance[s] = 0.25 * sum_b ||h[b,s,:]|| ----------------
// One wave (64 lanes) per token. Per batch row: 768 floats = 192 float4, 3 per lane.
__global__ __launch_bounds__(256) void importance_kernel(const float4* __restrict__ h4,
                                                         uint32_t* __restrict__ imp_u) {
    const int D4 = D_DIM / 4; // 192
    int wave = (blockIdx.x * blockDim.x + threadIdx.x) >> 6;
    int lane = threadIdx.x & 63;
    if (wave >= S_TOK) return;
    float acc = 0.f;
#pragma unroll
    for (int b = 0; b < B_SZ; ++b) {
        const float4* row = h4 + ((size_t)b * S_TOK + (size_t)wave) * D4;
        float ss = 0.f;
#pragma unroll
        for (int j = 0; j < 3; ++j) {
            float4 v = row[lane + 64 * j];
            ss += v.x * v.x + v.y * v.y + v.z * v.z + v.w * v.w;
        }
#pragma unroll
        for (int off = 32; off >= 1; off >>= 1) ss += __shfl_xor(ss, off);
        acc += sqrtf(ss);
    }
    // norms are >= 0, so float bits compare as uint32 — store bits directly
    if (lane == 0) imp_u[wave] = __float_as_uint(acc * 0.25f);
}

// ---------------- Kernel 2: all-pairs partial rank ----------------
// rank(s) = #{s' : key[s'] > key[s]  ||  (key[s'] == key[s] && s' < s)}.
// Block (grp, c): tokens [grp*256, grp*256+256) vs slice keys [c*256, c*256+256).
// Slice reads are wave-uniform -> scalar loads through K$; no LDS, no atomics.
__global__ __launch_bounds__(256) void rank_kernel(const uint32_t* __restrict__ imp_u,
                                                   uint32_t* __restrict__ partial) {
    const int grp = blockIdx.x >> 5;   // 0..31
    const int c   = blockIdx.x & 31;   // 0..31
    const int s   = grp * 256 + threadIdx.x;
    const uint32_t ks = imp_u[s];
    const uint4* slice4 = (const uint4*)(imp_u + c * SLICE);
    uint32_t cnt = 0;
#pragma unroll 8
    for (int j4 = 0; j4 < SLICE / 4; ++j4) {
        uint4 kv = slice4[j4];                 // uniform -> s_load_dwordx4
        const int jb = c * SLICE + j4 * 4;
        cnt += (kv.x > ks || (kv.x == ks && (jb + 0) < s)) ? 1u : 0u;
        cnt += (kv.y > ks || (kv.y == ks && (jb + 1) < s)) ? 1u : 0u;
        cnt += (kv.z > ks || (kv.z == ks && (jb + 2) < s)) ? 1u : 0u;
        cnt += (kv.w > ks || (kv.w == ks && (jb + 3) < s)) ? 1u : 0u;
    }
    partial[c * S_TOK + s] = cnt;              // coalesced
}

// ---------------- Kernel 3: sum partials -> rank; if rank < 512 gather row ----------
// 8192 blocks x 64 threads (1 wave). Lanes 0..31 read the 32 partials, shfl-reduce;
// blocks with rank >= 512 exit; survivors write out[rank] = 0.25 * sum_b h[b,s,:].
__global__ __launch_bounds__(64) void sum_gather_kernel(const uint32_t* __restrict__ partial,
                                                        const float4* __restrict__ h4,
                                                        float4* __restrict__ out4) {
    const int s = blockIdx.x;
    const int lane = threadIdx.x;  // 0..63
    uint32_t v = (lane < NSLICE) ? partial[lane * S_TOK + s] : 0u;
#pragma unroll
    for (int off = 16; off >= 1; off >>= 1) v += __shfl_down(v, off);
    const int rank = (int)__shfl(v, 0);
    if (rank >= K_TOP) return;

    const int D4 = D_DIM / 4;  // 192
    const size_t SD4 = (size_t)S_TOK * D4;
    const float4* base = h4 + (size_t)s * D4;
#pragma unroll
    for (int j = 0; j < 3; ++j) {
        int d = lane + 64 * j;
        float4 a = base[d];
        float4 b = base[d + SD4];
        float4 c = base[d + 2 * SD4];
        float4 e = base[d + 3 * SD4];
        float4 r;
        r.x = 0.25f * (a.x + b.x + c.x + e.x);
        r.y = 0.25f * (a.y + b.y + c.y + e.y);
        r.z = 0.25f * (a.z + b.z + c.z + e.z);
        r.w = 0.25f * (a.w + b.w + c.w + e.w);
        out4[(size_t)rank * D4 + d] = r;
    }
}

extern "C" void kernel_launch(void* const* d_in, const int* in_sizes, int n_in,
                              void* d_out, int out_size, void* d_ws, size_t ws_size,
                              hipStream_t stream) {
    const float* h = (const float*)d_in[0];
    // d_in[1] (memory) is dead: k == MEMORY_SIZE, every row is overwritten.
    float* out = (float*)d_out;
    uint32_t* imp_u = (uint32_t*)d_ws;
    uint32_t* partial = (uint32_t*)((char*)d_ws + S_TOK * sizeof(uint32_t));

    importance_kernel<<<S_TOK / 4, 256, 0, stream>>>((const float4*)h, imp_u);
    rank_kernel<<<NSLICE * (S_TOK / 256), 256, 0, stream>>>(imp_u, partial);
    sum_gather_kernel<<<S_TOK, 64, 0, stream>>>(partial, (const float4*)h, (float4*)out);
}